// Round 10
// baseline (394.580 us; speedup 1.0000x reference)
//
#include <hip/hip_runtime.h>
#include <hip/hip_bf16.h>

// DecoderInputEmbedding — B=4, T=1024, F=6144 (SW=96 x FB=64), EMB=512, H=3, dh=32.
// All inputs fp32 (o_enc int32), output fp32. Internals bf16 (2%-rel threshold).
// R20: attn_ffn re-merged (R16-exact monolith, 171.4us; R19 split cost +12us
// round-trip and proved ffn/gemm/prep/final all <92.4us). gemm rebuilt:
// BM=128/BN=64, 512 thr (8 waves, 4x2 wave-tiles 32x32), BK=64 dbuf, 48KB
// LDS, grid=256=1 block/CU (R18's 128-block error fixed: all CUs busy).
// bx=id&31, by=id>>5 co-locates the 8 same-A-panel blocks per XCD
// (32 = 0 mod 8) -> A re-reads L2-hit. Transit 780->~240MB.
// R19 data: attn_ab 92.5 steady; gemm inferred 85-92 (just under top-5 line).
//
// ws layout (bytes):
//   M    @ 0          bf16 4096x6144
//   Y    @ 50331648   fp32 4096x512
//   sums @ 58720256   2 floats
//   bids @ 58720320   4x1024 int
//   Wc   @ 58736768   canonical bf16 weights (~6.5MB)

typedef __attribute__((ext_vector_type(8))) short bf16x8;   // 8 bf16 = 4 VGPR
typedef __attribute__((ext_vector_type(4))) float f32x4;    // MFMA C/D

struct PtrTab { const void* p[16]; };

enum : int {
  O_WQT = 0,        // [96][104]  W^T padded
  O_BQ  = 9984,
  O_WKT = 10080,
  O_BK  = 20064,
  O_WVT = 20160,
  O_BV  = 30144,
  O_ER  = 30240,    // [64][32]
  O_W1T = 32288,    // [384][104]
  O_B1  = 72224,
  O_W2C = 72608,    // [12][96][40]  W2^T k-chunks of 32, padded to 40
  O_B2  = 118688,
  O_WET = 118784    // [8 nt][96 kt][64 n'][64 k']
};

__device__ __forceinline__ float b2f(__hip_bfloat16 v) { return __bfloat162float(v); }
__device__ __forceinline__ __hip_bfloat16 f2b(float v) { return __float2bfloat16(v); }

// async global->LDS 16B: wave-uniform LDS base, per-lane global src (lane*16 implicit)
__device__ __forceinline__ void gload16(const void* g, void* l) {
    __builtin_amdgcn_global_load_lds(
        (const __attribute__((address_space(1))) void*)g,
        (__attribute__((address_space(3))) void*)l, 16, 0, 0);
}

// prep: We transpose + weight convert + zero sums + segid scan (blocks 0..3)
__global__ __launch_bounds__(256) void prep_kernel(PtrTab tab,
                                                   __hip_bfloat16* __restrict__ Wc,
                                                   float* __restrict__ sums,
                                                   int* __restrict__ bids)
{
    __shared__ __hip_bfloat16 tile[64][65];
    const int bid = blockIdx.x, tid = threadIdx.x;
    // ---- We (6144x512) -> blocked WeT: [nt][kt][n'][k'] ----
    const int kt = bid % 96, nt = bid / 96;
    const float* We = (const float*)tab.p[14];
    const int k0 = kt * 64, n0 = nt * 64;
    for (int e = tid; e < 4096; e += 256) {
        int kk = e >> 6, nn = e & 63;
        tile[nn][kk] = f2b(We[(size_t)(k0 + kk) * 512 + n0 + nn]);
    }
    __syncthreads();
    __hip_bfloat16* dstT = Wc + O_WET + ((size_t)nt * 96 + kt) * 4096;
    for (int e = tid; e < 4096; e += 256) dstT[e] = tile[e >> 6][e & 63];

    // ---- converts (grid-stride over the whole grid) ----
    const int g = bid * 256 + tid;
    const int stride = gridDim.x * 256;
    const float* Wq = (const float*)tab.p[3];
    const float* bq = (const float*)tab.p[4];
    const float* Wk = (const float*)tab.p[5];
    const float* bk = (const float*)tab.p[6];
    const float* Wv = (const float*)tab.p[7];
    const float* bv = (const float*)tab.p[8];
    const float* Er = (const float*)tab.p[9];
    const float* W1 = (const float*)tab.p[10];
    const float* b1 = (const float*)tab.p[11];
    const float* W2 = (const float*)tab.p[12];
    const float* b2 = (const float*)tab.p[13];

    for (int t = 0; t < 3; ++t) {
        const float* W = (t == 0 ? Wq : t == 1 ? Wk : Wv);
        __hip_bfloat16* d = Wc + t * 10080;
        for (int i = g; i < 9984; i += stride) {
            int j = i / 104, c = i - j * 104;
            d[i] = (c < 96) ? f2b(W[c * 96 + j]) : f2b(0.0f);
        }
    }
    for (int i = g; i < 96; i += stride) {
        Wc[O_BQ + i] = f2b(bq[i]);
        Wc[O_BK + i] = f2b(bk[i]);
        Wc[O_BV + i] = f2b(bv[i]);
        Wc[O_B2 + i] = f2b(b2[i]);
    }
    for (int i = g; i < 2048; i += stride) Wc[O_ER + i] = f2b(Er[i]);
    for (int i = g; i < 39936; i += stride) {
        int j = i / 104, c = i - j * 104;
        Wc[O_W1T + i] = (c < 96) ? f2b(W1[c * 384 + j]) : f2b(0.0f);
    }
    for (int i = g; i < 384; i += stride) Wc[O_B1 + i] = f2b(b1[i]);
    for (int i = g; i < 46080; i += stride) {
        int kc = i / 3840, r = i - kc * 3840;
        int nn = r / 40, kk = r - nn * 40;
        Wc[O_W2C + i] = (kk < 32) ? f2b(W2[(kc * 32 + kk) * 96 + nn]) : f2b(0.0f);
    }
    if (g < 2) sums[g] = 0.f;

    // ---- segid scan (blocks 0..3, one batch row each; tile is dead) ----
    if (bid < 4) {
        __syncthreads();
        int* ts = (int*)tile;
        const int* o = (const int*)tab.p[1] + bid * 1024;
        int v0 = o[4 * tid], v1 = o[4 * tid + 1], v2 = o[4 * tid + 2], v3 = o[4 * tid + 3];
        int p0 = v0, p1 = p0 + v1, p2 = p1 + v2, p3 = p2 + v3;
        ts[tid] = p3;
        __syncthreads();
        for (int off = 1; off < 256; off <<= 1) {
            int mine = ts[tid];
            int add = (tid >= off) ? ts[tid - off] : 0;
            __syncthreads();
            ts[tid] = mine + add;
            __syncthreads();
        }
        const int excl = (tid > 0) ? ts[tid - 1] : 0;
        const int off0 = o[0];
        int* bd = bids + bid * 1024;
        bd[4 * tid]     = excl + p0 - off0;
        bd[4 * tid + 1] = excl + p1 - off0;
        bd[4 * tid + 2] = excl + p2 - off0;
        bd[4 * tid + 3] = excl + p3 - off0;
    }
}

// Fragment layouts (HW-verified): A: m=lane&15, k=quad*8+j; B from B^T same;
// C/D: col=lane&15 (= B-row), row=quad*4+reg (= A-row).
// Swapped QK^T (phase B): mfma(K-frag, Q-frag) -> lane ln holds row ql=16w+ln
// of S, key positions m = 16*tn + 4*quad + r.
__global__ __launch_bounds__(256, 4) void attn_ffn_kernel(
    const float* __restrict__ x, const __hip_bfloat16* __restrict__ Wc,
    __hip_bfloat16* __restrict__ M)
{
    const int n = blockIdx.x, tid = threadIdx.x;
    const int w = tid >> 6, lane = tid & 63, quad = lane >> 4, ln = lane & 15;

    __shared__ __align__(16) char smem[40448];
    __hip_bfloat16* xs  = (__hip_bfloat16*)(smem);          // [64][104] x / scratch / att
    __hip_bfloat16* wb  = (__hip_bfloat16*)(smem);          // 9984 B FFN1 stage (phase C)
    __hip_bfloat16* kS  = (__hip_bfloat16*)(smem + 13312);  // [64][104] Qscr / K
    __hip_bfloat16* vT  = (__hip_bfloat16*)(smem + 26624);  // [96][72]  V^T
    __hip_bfloat16* hid = (__hip_bfloat16*)(smem + 13312);  // [64][200] (phase C)

    const f32x4 z4 = {0.f, 0.f, 0.f, 0.f};
    const int rowb = 16 * w + quad * 4;
    const int myrow = 16 * w + ln;                          // wave-local x-row

    bf16x8 wf[9], wfn[9];
    #pragma unroll
    for (int i = 0; i < 9; ++i)
        wf[i] = *(const bf16x8*)(Wc + O_WQT + ((i % 3) * 16 + ln) * 104 + (i / 3) * 32 + quad * 8);

    {
        const float* xb = x + (size_t)n * 6144;
        const int sb = w * 24;
        for (int c = 0; c < 3; ++c) {
            float v[8];
            #pragma unroll
            for (int j = 0; j < 8; ++j) v[j] = xb[(sb + c * 8 + j) * 64 + lane];
            union { __hip_bfloat16 h[8]; bf16x8 v8; } pk;
            #pragma unroll
            for (int j = 0; j < 8; ++j) pk.h[j] = f2b(v[j]);
            *(bf16x8*)(xs + lane * 104 + sb + c * 8) = pk.v8;
        }
    }
    __syncthreads();                                        // barrier 1

    bf16x8 af[3];
    #pragma unroll
    for (int ks = 0; ks < 3; ++ks)
        af[ks] = *(const bf16x8*)(xs + myrow * 104 + ks * 32 + quad * 8);

    bf16x8 aqr[3];                                          // Q A-frags (regs)

    // ---------- phase A: Q/K/V via register weight frags (no barriers) ----------
    for (int st = 0; st < 6; ++st) {
        const int t = st >> 1, half = st & 1;
        if (st < 5) {
            const __hip_bfloat16* nb = Wc + ((st + 1) >> 1) * 10080 + ((st + 1) & 1) * 4992;
            #pragma unroll
            for (int i = 0; i < 9; ++i)
                wfn[i] = *(const bf16x8*)(nb + ((i % 3) * 16 + ln) * 104 + (i / 3) * 32 + quad * 8);
        }
        f32x4 acc[3] = {z4, z4, z4};
        const int j0 = half * 48;
        const __hip_bfloat16* bt = Wc + 9984 + t * 10080;
        if (t < 2) {                                        // Q / K: swapped + packed
            #pragma unroll
            for (int ks = 0; ks < 3; ++ks)
                #pragma unroll
                for (int ct = 0; ct < 3; ++ct)
                    acc[ct] = __builtin_amdgcn_mfma_f32_16x16x32_bf16(wf[ks * 3 + ct], af[ks], acc[ct], 0, 0, 0);
            #pragma unroll
            for (int ct = 0; ct < 3; ++ct) {
                const int cb = j0 + ct * 16 + 4 * quad;
                union { uint2 u; __hip_bfloat16 h[4]; } bu;
                bu.u = *(const uint2*)(bt + cb);
                union { __hip_bfloat16 h4[4]; uint2 u; } pk;
                #pragma unroll
                for (int r = 0; r < 4; ++r) pk.h4[r] = f2b(acc[ct][r] + b2f(bu.h[r]));
                *(uint2*)(kS + myrow * 104 + cb) = pk.u;
            }
        } else {                                            // V: original -> vT uint2
            #pragma unroll
            for (int ks = 0; ks < 3; ++ks)
                #pragma unroll
                for (int ct = 0; ct < 3; ++ct)
                    acc[ct] = __builtin_amdgcn_mfma_f32_16x16x32_bf16(af[ks], wf[ks * 3 + ct], acc[ct], 0, 0, 0);
            #pragma unroll
            for (int ct = 0; ct < 3; ++ct) {
                int col = j0 + ct * 16 + ln;
                float bb = b2f(bt[col]);
                union { __hip_bfloat16 h4[4]; uint2 u; } pk;
                #pragma unroll
                for (int r = 0; r < 4; ++r) pk.h4[r] = f2b(acc[ct][r] + bb);
                *(uint2*)(vT + col * 72 + rowb) = pk.u;
            }
        }
        if (t == 0 && half == 1) {
            #pragma unroll
            for (int h = 0; h < 3; ++h)
                aqr[h] = *(const bf16x8*)(kS + myrow * 104 + h * 32 + quad * 8);
        }
        #pragma unroll
        for (int i = 0; i < 9; ++i) wf[i] = wfn[i];
    }

    bf16x8 erf[4];
    #pragma unroll
    for (int tn = 0; tn < 4; ++tn)
        erf[tn] = *(const bf16x8*)(Wc + O_ER + (16 * tn + ln) * 32 + quad * 8);
    __syncthreads();                                        // barrier 2: K/V visible

    bf16x8 pf0, pf1, pf2;
    {
        const bf16x8* src = (const bf16x8*)(Wc + O_W1T);
        pf0 = src[tid]; pf1 = src[tid + 256];
        if (tid + 512 < 624) pf2 = src[tid + 512];
    }

    // ---------- phase B: swapped-operand attention (barrier-free) ----------
    __hip_bfloat16* S2 = xs + 32;
    const int ql = myrow;
    const int sshift = 63 - ql;
    f32x4 oacc[3][2] = {{z4, z4}, {z4, z4}, {z4, z4}};

    #pragma unroll
    for (int h = 0; h < 3; ++h) {
        const int c0 = h * 32;
        bf16x8 aq = aqr[h];
        #pragma unroll
        for (int tn = 0; tn < 4; ++tn) {
            f32x4 q4 = __builtin_amdgcn_mfma_f32_16x16x32_bf16(erf[tn], aq, z4, 0, 0, 0);
            #pragma unroll
            for (int r = 0; r < 4; ++r) {
                int e = 16 * tn + 4 * quad + r;
                if (e >= sshift) S2[ql * 104 + (e - sshift)] = f2b(q4[r]);
            }
        }
        float sco[4][4];
        #pragma unroll
        for (int tn = 0; tn < 4; ++tn) {
            bf16x8 kf = *(const bf16x8*)(kS + (16 * tn + ln) * 104 + c0 + quad * 8);
            f32x4 s1 = __builtin_amdgcn_mfma_f32_16x16x32_bf16(kf, aq, z4, 0, 0, 0);
            #pragma unroll
            for (int r = 0; r < 4; ++r) sco[tn][r] = s1[r];
        }
        #pragma unroll
        for (int tn = 0; tn < 4; ++tn) {
            union { __hip_bfloat16 h4[4]; uint2 u; } sr;
            sr.u = *(const uint2*)(S2 + ql * 104 + 16 * tn + 4 * quad);
            #pragma unroll
            for (int r = 0; r < 4; ++r) {
                int m = 16 * tn + 4 * quad + r;
                sco[tn][r] = (m <= ql)
                    ? (sco[tn][r] + b2f(sr.h4[r])) * 0.17677669529663687f
                    : -3.0e38f;
            }
        }
        float mt[4];
        #pragma unroll
        for (int tn = 0; tn < 4; ++tn)
            mt[tn] = fmaxf(fmaxf(sco[tn][0], sco[tn][1]), fmaxf(sco[tn][2], sco[tn][3]));
        float mx = fmaxf(fmaxf(mt[0], mt[1]), fmaxf(mt[2], mt[3]));
        mx = fmaxf(mx, __shfl_xor(mx, 16, 64));
        mx = fmaxf(mx, __shfl_xor(mx, 32, 64));
        float st_[4];
        #pragma unroll
        for (int tn = 0; tn < 4; ++tn) {
            #pragma unroll
            for (int r = 0; r < 4; ++r) sco[tn][r] = __expf(sco[tn][r] - mx);
            st_[tn] = (sco[tn][0] + sco[tn][1]) + (sco[tn][2] + sco[tn][3]);
        }
        float sum = (st_[0] + st_[1]) + (st_[2] + st_[3]);
        sum += __shfl_xor(sum, 16, 64);
        sum += __shfl_xor(sum, 32, 64);
        const float inv = 1.0f / sum;
        #pragma unroll
        for (int tn = 0; tn < 4; ++tn) {
            union { __hip_bfloat16 h4[4]; uint2 u; } pk;
            #pragma unroll
            for (int r = 0; r < 4; ++r) pk.h4[r] = f2b(sco[tn][r] * inv);
            *(uint2*)(S2 + ql * 104 + 16 * tn + 4 * quad) = pk.u;
        }
        #pragma unroll
        for (int ks2 = 0; ks2 < 2; ++ks2) {
            bf16x8 pa = *(const bf16x8*)(S2 + ql * 104 + ks2 * 32 + quad * 8);
            #pragma unroll
            for (int t2 = 0; t2 < 2; ++t2) {
                bf16x8 vb = *(const bf16x8*)(vT + (c0 + 16 * t2 + ln) * 72 + ks2 * 32 + quad * 8);
                oacc[h][t2] = __builtin_amdgcn_mfma_f32_16x16x32_bf16(vb, pa, oacc[h][t2], 0, 0, 0);
            }
        }
    }
    // deferred att-out: packed uint2 (4 consecutive d, own row)
    #pragma unroll
    for (int h = 0; h < 3; ++h)
        #pragma unroll
        for (int t2 = 0; t2 < 2; ++t2) {
            union { __hip_bfloat16 h4[4]; uint2 u; } pk;
            #pragma unroll
            for (int r = 0; r < 4; ++r) pk.h4[r] = f2b(oacc[h][t2][r]);
            *(uint2*)(xs + myrow * 104 + h * 32 + 16 * t2 + 4 * quad) = pk.u;
        }

    // ---------- phase C: FFN (FFN1 LDS-pipelined; FFN2 register frags) ----------
    bf16x8 cf[3];
    #pragma unroll
    for (int ks = 0; ks < 3; ++ks)
        cf[ks] = *(const bf16x8*)(xs + myrow * 104 + ks * 32 + quad * 8);

    f32x4 acc2[6] = {z4, z4, z4, z4, z4, z4};
    bf16x8 w2f[6], w2fn[6];
    for (int jh = 0; jh < 2; ++jh) {
        for (int cc = 0; cc < 4; ++cc) {
            const int j0g = jh * 192 + cc * 48;
            __syncthreads();
            {
                bf16x8* dst = (bf16x8*)wb;
                dst[tid] = pf0;
                dst[tid + 256] = pf1;
                if (tid + 512 < 624) dst[tid + 512] = pf2;
                if (cc < 3) {
                    const bf16x8* src = (const bf16x8*)(Wc + O_W1T + jh * 19968 + (cc + 1) * 4992);
                    pf0 = src[tid]; pf1 = src[tid + 256];
                    if (tid + 512 < 624) pf2 = src[tid + 512];
                } else {
                    const __hip_bfloat16* nb = Wc + O_W2C + (jh * 6) * 3840;
                    #pragma unroll
                    for (int ct = 0; ct < 6; ++ct)
                        w2f[ct] = *(const bf16x8*)(nb + (ct * 16 + ln) * 40 + quad * 8);
                }
            }
            __syncthreads();
            f32x4 a1[3] = {z4, z4, z4};
            #pragma unroll
            for (int ks = 0; ks < 3; ++ks) {
                #pragma unroll
                for (int ct = 0; ct < 3; ++ct) {
                    bf16x8 b = *(const bf16x8*)(wb + (ct * 16 + ln) * 104 + ks * 32 + quad * 8);
                    a1[ct] = __builtin_amdgcn_mfma_f32_16x16x32_bf16(b, cf[ks], a1[ct], 0, 0, 0);
                }
            }
            #pragma unroll
            for (int ct = 0; ct < 3; ++ct) {
                const int cb = ct * 16 + 4 * quad;
                union { uint2 u; __hip_bfloat16 h[4]; } bu;
                bu.u = *(const uint2*)(Wc + O_B1 + j0g + cb);
                union { __hip_bfloat16 h4[4]; uint2 u; } pk;
                #pragma unroll
                for (int r = 0; r < 4; ++r)
                    pk.h4[r] = f2b(fmaxf(a1[ct][r] + b2f(bu.h[r]), 0.f));
                *(uint2*)(hid + myrow * 200 + cc * 48 + cb) = pk.u;
            }
        }
        for (int kc = 0; kc < 6; ++kc) {
            if (kc < 5) {
                const __hip_bfloat16* nb = Wc + O_W2C + (jh * 6 + kc + 1) * 3840;
                #pragma unroll
                for (int ct = 0; ct < 6; ++ct)
                    w2fn[ct] = *(const bf16x8*)(nb + (ct * 16 + ln) * 40 + quad * 8);
            } else if (jh == 0) {
                const bf16x8* src = (const bf16x8*)(Wc + O_W1T + 19968);
                pf0 = src[tid]; pf1 = src[tid + 256];
                if (tid + 512 < 624) pf2 = src[tid + 512];
            }
            bf16x8 a = *(const bf16x8*)(hid + myrow * 200 + kc * 32 + quad * 8);
            #pragma unroll
            for (int ct = 0; ct < 6; ++ct)
                acc2[ct] = __builtin_amdgcn_mfma_f32_16x16x32_bf16(a, w2f[ct], acc2[ct], 0, 0, 0);
            if (kc < 5) {
                #pragma unroll
                for (int ct = 0; ct < 6; ++ct) w2f[ct] = w2fn[ct];
            }
        }
    }

    __hip_bfloat16* Mg = M + (size_t)n * 6144;
    #pragma unroll
    for (int ct = 0; ct < 6; ++ct) {
        int d = ct * 16 + ln;
        float bb = b2f(Wc[O_B2 + d]);
        union { __hip_bfloat16 h4[4]; uint2 u; } pk;
        #pragma unroll
        for (int r = 0; r < 4; ++r) pk.h4[r] = f2b(acc2[ct][r] + bb);
        *(uint2*)((char*)Mg + (size_t)(d * 64 + rowb) * 2) = pk.u;
    }
}

// Y = A @ We + be, mean/var fused. R20: BM=128/BN=64, 512 thr (8 waves as
// 4x2 tiles of 32x32), BK=64 dbuf, 48KB LDS, grid 256 = 1 block/CU.
// Staging = R17's verified pattern (128B rows, XOR (row&7)<<4 both sides).
// bx=id&31, by=id>>5: same-A-panel blocks share an XCD (round-robin, 32=0 mod 8).
__global__ __launch_bounds__(512) void gemm_kernel(
    const __hip_bfloat16* __restrict__ A,    // 4096 x 6144 (M workspace)
    const __hip_bfloat16* __restrict__ Wc,
    const float* __restrict__ be,            // fp32 bias (512)
    float* __restrict__ Y,                   // 4096 x 512
    float* __restrict__ sums)                // 2 floats (pre-zeroed)
{
    __shared__ __align__(16) char gsm[49152];   // As[2] 16KB each @0, Bs[2] 8KB each @32768
    __shared__ float r1s[8], r2s[8];
    const int id = blockIdx.x;
    const int bx = id & 31, by = id >> 5;        // same bx -> same XCD (id%8 = bx&7)
    const int row0 = bx * 128, col0 = by * 64;
    const int tid = threadIdx.x;
    const int w = tid >> 6, lane = tid & 63, quad = lane >> 4, ln = lane & 15;
    const int wr = w & 3, wc = w >> 2;           // 4x2 wave tiles of 32x32

    const f32x4 z4 = {0.f, 0.f, 0.f, 0.f};
    f32x4 acc[2][2] = {{z4, z4}, {z4, z4}};

    // stage 128x64 A (16KB, 2 issues) + 64x64 B (8KB, 1 issue) for k-tile kt.
    auto stage = [&](int buf, int kt) {          // kt in [0,96)
        char* Ab = gsm + buf * 16384;
        char* Bb = gsm + 32768 + buf * 8192;
        #pragma unroll
        for (int p = 0; p < 2; ++p) {
            const int b = p * 8192 + tid * 16;
            const int row = b >> 7;                          // 128 B per row
            const int cb = (b & 127) ^ ((row & 7) << 4);     // involution in-row
            const int col = cb >> 1;                         // element, mult of 8
            gload16(A + (size_t)(row0 + row) * 6144 + kt * 64 + col,
                    Ab + p * 8192 + w * 1024);
        }
        {
            const int b = tid * 16;
            const int row = b >> 7;                          // n' 0..63
            const int cb = (b & 127) ^ ((row & 7) << 4);
            const int col = cb >> 1;
            gload16(Wc + O_WET + ((size_t)by * 96 + kt) * 4096 + row * 64 + col,
                    Bb + w * 1024);
        }
    };

    stage(0, 0);
    __syncthreads();

    for (int kt = 0; kt < 96; ++kt) {
        const int cur = kt & 1;
        if (kt < 95) stage(cur ^ 1, kt + 1);                 // async, lands at barrier
        const char* Ab = gsm + cur * 16384;
        const char* Bb = gsm + 32768 + cur * 8192;
        const int key = (ln & 7) << 4;
        #pragma unroll
        for (int ks = 0; ks < 2; ++ks) {
            const int ko = ks * 64 + quad * 16;              // k-byte offset
            bf16x8 a[2], bf[2];
            #pragma unroll
            for (int i = 0; i < 2; ++i)
                a[i] = *(const bf16x8*)(Ab + (32 * wr + 16 * i + ln) * 128 + (ko ^ key));
            #pragma unroll
            for (int j = 0; j < 2; ++j)
                bf[j] = *(const bf16x8*)(Bb + (32 * wc + 16 * j + ln) * 128 + (ko ^ key));
            #pragma unroll
            for (int i = 0; i < 2; ++i)
                #pragma unroll
                for (int j = 0; j < 2; ++j)
                    acc[i][j] = __builtin_amdgcn_mfma_f32_16x16x32_bf16(a[i], bf[j], acc[i][j], 0, 0, 0);
        }
        __syncthreads();                                     // drains vmcnt: stage landed
    }

    float s = 0.f, s2 = 0.f;
    #pragma unroll
    for (int i = 0; i < 2; ++i)
        #pragma unroll
        for (int j = 0; j < 2; ++j) {
            const int colg = col0 + 32 * wc + 16 * j + ln;
            const float bb = be[colg];
            #pragma unroll
            for (int r = 0; r < 4; ++r) {
                float v = acc[i][j][r] + bb;
                Y[(size_t)(row0 + 32 * wr + 16 * i + quad * 4 + r) * 512 + colg] = v;
                s += v; s2 += v * v;
            }
        }
    #pragma unroll
    for (int off = 1; off < 64; off <<= 1) {
        s  += __shfl_xor(s, off, 64);
        s2 += __shfl_xor(s2, off, 64);
    }
    if (lane == 0) { r1s[w] = s; r2s[w] = s2; }
    __syncthreads();
    if (tid == 0) {
        float t1 = 0.f, t2 = 0.f;
        #pragma unroll
        for (int i = 0; i < 8; ++i) { t1 += r1s[i]; t2 += r2s[i]; }
        atomicAdd(&sums[0], t1);
        atomicAdd(&sums[1], t2);
    }
}

__global__ __launch_bounds__(256) void final_kernel(
    const float* __restrict__ Y, const int* __restrict__ bids,
    const float* __restrict__ sums, const float* __restrict__ r_enc,
    float* __restrict__ out)
{
    const int bt = blockIdx.x;
    const int b = bt >> 10, t = bt & 1023;
    const float mu = sums[0] * (1.0f / 2097152.0f);
    const float var = sums[1] * (1.0f / 2097152.0f) - mu * mu;
    const float rstd = rsqrtf(var + 1e-8f);
    const int* bid = bids + b * 1024;
    const int my = bid[t];
    const bool is_start = (t == 0) || (bid[t - 1] != my);
    int t2 = t + 1;
    float invc = 0.f;
    if (is_start) {
        while (t2 < 1024 && bid[t2] == my) ++t2;
        invc = 1.0f / (float)(t2 - t);
    }
    for (int e = threadIdx.x; e < 512; e += 256) {
        const size_t base = (size_t)bt * 512 + e;
        float res = (Y[base] - mu) * rstd + r_enc[base];
        if (is_start) {
            float s = 0.f;
            for (int tt = t; tt < t2; ++tt)
                s += (Y[((size_t)(b * 1024 + tt)) * 512 + e] - mu) * rstd;
            res += s * invc;
        }
        out[base] = res;
    }
}

extern "C" void kernel_launch(void* const* d_in, const int* in_sizes, int n_in,
                              void* d_out, int out_size, void* d_ws, size_t ws_size,
                              hipStream_t stream) {
    PtrTab tab;
    for (int i = 0; i < 16; ++i) tab.p[i] = d_in[i];

    char* ws = (char*)d_ws;
    __hip_bfloat16* M  = (__hip_bfloat16*)ws;
    float* Y           = (float*)(ws + 50331648);
    float* sums        = (float*)(ws + 58720256);
    int*   bids        = (int*)(ws + 58720320);
    __hip_bfloat16* Wc = (__hip_bfloat16*)(ws + 58736768);

    prep_kernel<<<768, 256, 0, stream>>>(tab, Wc, sums, bids);
    attn_ffn_kernel<<<4096, 256, 0, stream>>>((const float*)d_in[0], Wc, M);
    gemm_kernel<<<256, 512, 0, stream>>>(M, Wc, (const float*)d_in[15], Y, sums);
    final_kernel<<<4096, 256, 0, stream>>>(Y, bids, sums, (const float*)d_in[2], (float*)d_out);
}

// Round 11
// 352.916 us; speedup vs baseline: 1.1181x; 1.1181x over previous
//
#include <hip/hip_runtime.h>
#include <hip/hip_bf16.h>

// DecoderInputEmbedding — B=4, T=1024, F=6144 (SW=96 x FB=64), EMB=512, H=3, dh=32.
// All inputs fp32 (o_enc int32), output fp32. Internals bf16 (2%-rel threshold).
// R21: dual-instance attn_ffn — each block processes rows n and n+2048 with
// SHARED weight fragments (wf/wfn, erf, pf, w2f/w2fn) and duplicated
// per-instance state (compile-time ii unroll, static indexing). Rationale:
// attn is dependency-latency-bound (R14: removing prefetch +60us) but
// TLP-insensitive (R13: occupancy 31->41 null) with VGPR only 64/512 ->
// fill stalls with ILP from a twin independent chain in the same wave.
// Also halves weight traffic and per-work-unit barriers. LDS 80896 ->
// 2 blocks/CU. gemm = R16-exact (R17/R18/R20 alternatives all lost).
//
// ws layout (bytes):
//   M    @ 0          bf16 4096x6144
//   Y    @ 50331648   fp32 4096x512
//   sums @ 58720256   2 floats
//   bids @ 58720320   4x1024 int
//   Wc   @ 58736768   canonical bf16 weights (~6.5MB)

typedef __attribute__((ext_vector_type(8))) short bf16x8;   // 8 bf16 = 4 VGPR
typedef __attribute__((ext_vector_type(4))) float f32x4;    // MFMA C/D

struct PtrTab { const void* p[16]; };

enum : int {
  O_WQT = 0,        // [96][104]  W^T padded
  O_BQ  = 9984,
  O_WKT = 10080,
  O_BK  = 20064,
  O_WVT = 20160,
  O_BV  = 30144,
  O_ER  = 30240,    // [64][32]
  O_W1T = 32288,    // [384][104]
  O_B1  = 72224,
  O_W2C = 72608,    // [12][96][40]  W2^T k-chunks of 32, padded to 40
  O_B2  = 118688,
  O_WET = 118784    // [8 nt][96 kt][64 n'][64 k']
};

__device__ __forceinline__ float b2f(__hip_bfloat16 v) { return __bfloat162float(v); }
__device__ __forceinline__ __hip_bfloat16 f2b(float v) { return __float2bfloat16(v); }

// async global->LDS 16B: wave-uniform LDS base, per-lane global src (lane*16 implicit)
__device__ __forceinline__ void gload16(const void* g, void* l) {
    __builtin_amdgcn_global_load_lds(
        (const __attribute__((address_space(1))) void*)g,
        (__attribute__((address_space(3))) void*)l, 16, 0, 0);
}

// prep: We transpose + weight convert + zero sums + segid scan (blocks 0..3)
__global__ __launch_bounds__(256) void prep_kernel(PtrTab tab,
                                                   __hip_bfloat16* __restrict__ Wc,
                                                   float* __restrict__ sums,
                                                   int* __restrict__ bids)
{
    __shared__ __hip_bfloat16 tile[64][65];
    const int bid = blockIdx.x, tid = threadIdx.x;
    // ---- We (6144x512) -> blocked WeT: [nt][kt][n'][k'] ----
    const int kt = bid % 96, nt = bid / 96;
    const float* We = (const float*)tab.p[14];
    const int k0 = kt * 64, n0 = nt * 64;
    for (int e = tid; e < 4096; e += 256) {
        int kk = e >> 6, nn = e & 63;
        tile[nn][kk] = f2b(We[(size_t)(k0 + kk) * 512 + n0 + nn]);
    }
    __syncthreads();
    __hip_bfloat16* dstT = Wc + O_WET + ((size_t)nt * 96 + kt) * 4096;
    for (int e = tid; e < 4096; e += 256) dstT[e] = tile[e >> 6][e & 63];

    // ---- converts (grid-stride over the whole grid) ----
    const int g = bid * 256 + tid;
    const int stride = gridDim.x * 256;
    const float* Wq = (const float*)tab.p[3];
    const float* bq = (const float*)tab.p[4];
    const float* Wk = (const float*)tab.p[5];
    const float* bk = (const float*)tab.p[6];
    const float* Wv = (const float*)tab.p[7];
    const float* bv = (const float*)tab.p[8];
    const float* Er = (const float*)tab.p[9];
    const float* W1 = (const float*)tab.p[10];
    const float* b1 = (const float*)tab.p[11];
    const float* W2 = (const float*)tab.p[12];
    const float* b2 = (const float*)tab.p[13];

    for (int t = 0; t < 3; ++t) {
        const float* W = (t == 0 ? Wq : t == 1 ? Wk : Wv);
        __hip_bfloat16* d = Wc + t * 10080;
        for (int i = g; i < 9984; i += stride) {
            int j = i / 104, c = i - j * 104;
            d[i] = (c < 96) ? f2b(W[c * 96 + j]) : f2b(0.0f);
        }
    }
    for (int i = g; i < 96; i += stride) {
        Wc[O_BQ + i] = f2b(bq[i]);
        Wc[O_BK + i] = f2b(bk[i]);
        Wc[O_BV + i] = f2b(bv[i]);
        Wc[O_B2 + i] = f2b(b2[i]);
    }
    for (int i = g; i < 2048; i += stride) Wc[O_ER + i] = f2b(Er[i]);
    for (int i = g; i < 39936; i += stride) {
        int j = i / 104, c = i - j * 104;
        Wc[O_W1T + i] = (c < 96) ? f2b(W1[c * 384 + j]) : f2b(0.0f);
    }
    for (int i = g; i < 384; i += stride) Wc[O_B1 + i] = f2b(b1[i]);
    for (int i = g; i < 46080; i += stride) {
        int kc = i / 3840, r = i - kc * 3840;
        int nn = r / 40, kk = r - nn * 40;
        Wc[O_W2C + i] = (kk < 32) ? f2b(W2[(kc * 32 + kk) * 96 + nn]) : f2b(0.0f);
    }
    if (g < 2) sums[g] = 0.f;

    // ---- segid scan (blocks 0..3, one batch row each; tile is dead) ----
    if (bid < 4) {
        __syncthreads();
        int* ts = (int*)tile;
        const int* o = (const int*)tab.p[1] + bid * 1024;
        int v0 = o[4 * tid], v1 = o[4 * tid + 1], v2 = o[4 * tid + 2], v3 = o[4 * tid + 3];
        int p0 = v0, p1 = p0 + v1, p2 = p1 + v2, p3 = p2 + v3;
        ts[tid] = p3;
        __syncthreads();
        for (int off = 1; off < 256; off <<= 1) {
            int mine = ts[tid];
            int add = (tid >= off) ? ts[tid - off] : 0;
            __syncthreads();
            ts[tid] = mine + add;
            __syncthreads();
        }
        const int excl = (tid > 0) ? ts[tid - 1] : 0;
        const int off0 = o[0];
        int* bd = bids + bid * 1024;
        bd[4 * tid]     = excl + p0 - off0;
        bd[4 * tid + 1] = excl + p1 - off0;
        bd[4 * tid + 2] = excl + p2 - off0;
        bd[4 * tid + 3] = excl + p3 - off0;
    }
}

// Fragment layouts (HW-verified): A: m=lane&15, k=quad*8+j; B from B^T same;
// C/D: col=lane&15 (= B-row), row=quad*4+reg (= A-row).
// Swapped QK^T (phase B): mfma(K-frag, Q-frag) -> lane ln holds row ql=16w+ln
// of S, key positions m = 16*tn + 4*quad + r.
// R21: two instances per block (n, n+2048); LDS stride 40448; weights shared.
__global__ __launch_bounds__(256, 2) void attn_ffn_kernel(
    const float* __restrict__ x, const __hip_bfloat16* __restrict__ Wc,
    __hip_bfloat16* __restrict__ M)
{
    const int n0b = blockIdx.x, tid = threadIdx.x;
    const int w = tid >> 6, lane = tid & 63, quad = lane >> 4, ln = lane & 15;

    __shared__ __align__(16) char smem[80896];
    __hip_bfloat16* xs[2]  = { (__hip_bfloat16*)(smem),
                               (__hip_bfloat16*)(smem + 40448) };
    __hip_bfloat16* kS[2]  = { (__hip_bfloat16*)(smem + 13312),
                               (__hip_bfloat16*)(smem + 40448 + 13312) };
    __hip_bfloat16* vT[2]  = { (__hip_bfloat16*)(smem + 26624),
                               (__hip_bfloat16*)(smem + 40448 + 26624) };
    __hip_bfloat16* wb     =   (__hip_bfloat16*)(smem);            // phase C (xs0 dead)
    __hip_bfloat16* hid[2] = { (__hip_bfloat16*)(smem + 13312),    // over kS0/vT0
                               (__hip_bfloat16*)(smem + 40448 + 13312) };

    const f32x4 z4 = {0.f, 0.f, 0.f, 0.f};
    const int rowb = 16 * w + quad * 4;
    const int myrow = 16 * w + ln;                          // wave-local x-row

    bf16x8 wf[9], wfn[9];
    #pragma unroll
    for (int i = 0; i < 9; ++i)
        wf[i] = *(const bf16x8*)(Wc + O_WQT + ((i % 3) * 16 + ln) * 104 + (i / 3) * 32 + quad * 8);

    // stage x for both instances
    #pragma unroll
    for (int ii = 0; ii < 2; ++ii) {
        const float* xb = x + (size_t)(n0b + ii * 2048) * 6144;
        const int sb = w * 24;
        for (int c = 0; c < 3; ++c) {
            float v[8];
            #pragma unroll
            for (int j = 0; j < 8; ++j) v[j] = xb[(sb + c * 8 + j) * 64 + lane];
            union { __hip_bfloat16 h[8]; bf16x8 v8; } pk;
            #pragma unroll
            for (int j = 0; j < 8; ++j) pk.h[j] = f2b(v[j]);
            *(bf16x8*)(xs[ii] + lane * 104 + sb + c * 8) = pk.v8;
        }
    }
    __syncthreads();                                        // barrier 1

    bf16x8 af[2][3];
    #pragma unroll
    for (int ii = 0; ii < 2; ++ii)
        #pragma unroll
        for (int ks = 0; ks < 3; ++ks)
            af[ii][ks] = *(const bf16x8*)(xs[ii] + myrow * 104 + ks * 32 + quad * 8);

    bf16x8 aqr[2][3];                                       // Q A-frags (regs)

    // ---------- phase A: Q/K/V, weights shared across instances ----------
    for (int st = 0; st < 6; ++st) {
        const int t = st >> 1, half = st & 1;
        if (st < 5) {
            const __hip_bfloat16* nb = Wc + ((st + 1) >> 1) * 10080 + ((st + 1) & 1) * 4992;
            #pragma unroll
            for (int i = 0; i < 9; ++i)
                wfn[i] = *(const bf16x8*)(nb + ((i % 3) * 16 + ln) * 104 + (i / 3) * 32 + quad * 8);
        }
        const int j0 = half * 48;
        const __hip_bfloat16* bt = Wc + 9984 + t * 10080;
        if (t < 2) {                                        // Q / K: swapped + packed
            #pragma unroll
            for (int ii = 0; ii < 2; ++ii) {
                f32x4 acc[3] = {z4, z4, z4};
                #pragma unroll
                for (int ks = 0; ks < 3; ++ks)
                    #pragma unroll
                    for (int ct = 0; ct < 3; ++ct)
                        acc[ct] = __builtin_amdgcn_mfma_f32_16x16x32_bf16(wf[ks * 3 + ct], af[ii][ks], acc[ct], 0, 0, 0);
                #pragma unroll
                for (int ct = 0; ct < 3; ++ct) {
                    const int cb = j0 + ct * 16 + 4 * quad;
                    union { uint2 u; __hip_bfloat16 h[4]; } bu;
                    bu.u = *(const uint2*)(bt + cb);
                    union { __hip_bfloat16 h4[4]; uint2 u; } pk;
                    #pragma unroll
                    for (int r = 0; r < 4; ++r) pk.h4[r] = f2b(acc[ct][r] + b2f(bu.h[r]));
                    *(uint2*)(kS[ii] + myrow * 104 + cb) = pk.u;
                }
            }
        } else {                                            // V: original -> vT uint2
            #pragma unroll
            for (int ii = 0; ii < 2; ++ii) {
                f32x4 acc[3] = {z4, z4, z4};
                #pragma unroll
                for (int ks = 0; ks < 3; ++ks)
                    #pragma unroll
                    for (int ct = 0; ct < 3; ++ct)
                        acc[ct] = __builtin_amdgcn_mfma_f32_16x16x32_bf16(af[ii][ks], wf[ks * 3 + ct], acc[ct], 0, 0, 0);
                #pragma unroll
                for (int ct = 0; ct < 3; ++ct) {
                    int col = j0 + ct * 16 + ln;
                    float bb = b2f(bt[col]);
                    union { __hip_bfloat16 h4[4]; uint2 u; } pk;
                    #pragma unroll
                    for (int r = 0; r < 4; ++r) pk.h4[r] = f2b(acc[ct][r] + bb);
                    *(uint2*)(vT[ii] + col * 72 + rowb) = pk.u;
                }
            }
        }
        if (t == 0 && half == 1) {
            #pragma unroll
            for (int ii = 0; ii < 2; ++ii)
                #pragma unroll
                for (int h = 0; h < 3; ++h)
                    aqr[ii][h] = *(const bf16x8*)(kS[ii] + myrow * 104 + h * 32 + quad * 8);
        }
        #pragma unroll
        for (int i = 0; i < 9; ++i) wf[i] = wfn[i];
    }

    bf16x8 erf[4];
    #pragma unroll
    for (int tn = 0; tn < 4; ++tn)
        erf[tn] = *(const bf16x8*)(Wc + O_ER + (16 * tn + ln) * 32 + quad * 8);
    __syncthreads();                                        // barrier 2: K/V visible

    bf16x8 pf0, pf1, pf2;
    {
        const bf16x8* src = (const bf16x8*)(Wc + O_W1T);
        pf0 = src[tid]; pf1 = src[tid + 256];
        if (tid + 512 < 624) pf2 = src[tid + 512];
    }

    // ---------- phase B: swapped-operand attention (barrier-free) ----------
    const int ql = myrow;
    const int sshift = 63 - ql;
    f32x4 oacc[2][3][2];
    #pragma unroll
    for (int ii = 0; ii < 2; ++ii)
        #pragma unroll
        for (int h = 0; h < 3; ++h)
            #pragma unroll
            for (int t2 = 0; t2 < 2; ++t2) oacc[ii][h][t2] = z4;

    #pragma unroll
    for (int h = 0; h < 3; ++h) {
        const int c0 = h * 32;
        #pragma unroll
        for (int ii = 0; ii < 2; ++ii) {
            __hip_bfloat16* S2 = xs[ii] + 32;
            bf16x8 aq = aqr[ii][h];
            #pragma unroll
            for (int tn = 0; tn < 4; ++tn) {
                f32x4 q4 = __builtin_amdgcn_mfma_f32_16x16x32_bf16(erf[tn], aq, z4, 0, 0, 0);
                #pragma unroll
                for (int r = 0; r < 4; ++r) {
                    int e = 16 * tn + 4 * quad + r;
                    if (e >= sshift) S2[ql * 104 + (e - sshift)] = f2b(q4[r]);
                }
            }
            float sco[4][4];
            #pragma unroll
            for (int tn = 0; tn < 4; ++tn) {
                bf16x8 kf = *(const bf16x8*)(kS[ii] + (16 * tn + ln) * 104 + c0 + quad * 8);
                f32x4 s1 = __builtin_amdgcn_mfma_f32_16x16x32_bf16(kf, aq, z4, 0, 0, 0);
                #pragma unroll
                for (int r = 0; r < 4; ++r) sco[tn][r] = s1[r];
            }
            #pragma unroll
            for (int tn = 0; tn < 4; ++tn) {
                union { __hip_bfloat16 h4[4]; uint2 u; } sr;
                sr.u = *(const uint2*)(S2 + ql * 104 + 16 * tn + 4 * quad);
                #pragma unroll
                for (int r = 0; r < 4; ++r) {
                    int m = 16 * tn + 4 * quad + r;
                    sco[tn][r] = (m <= ql)
                        ? (sco[tn][r] + b2f(sr.h4[r])) * 0.17677669529663687f
                        : -3.0e38f;
                }
            }
            float mt[4];
            #pragma unroll
            for (int tn = 0; tn < 4; ++tn)
                mt[tn] = fmaxf(fmaxf(sco[tn][0], sco[tn][1]), fmaxf(sco[tn][2], sco[tn][3]));
            float mx = fmaxf(fmaxf(mt[0], mt[1]), fmaxf(mt[2], mt[3]));
            mx = fmaxf(mx, __shfl_xor(mx, 16, 64));
            mx = fmaxf(mx, __shfl_xor(mx, 32, 64));
            float st_[4];
            #pragma unroll
            for (int tn = 0; tn < 4; ++tn) {
                #pragma unroll
                for (int r = 0; r < 4; ++r) sco[tn][r] = __expf(sco[tn][r] - mx);
                st_[tn] = (sco[tn][0] + sco[tn][1]) + (sco[tn][2] + sco[tn][3]);
            }
            float sum = (st_[0] + st_[1]) + (st_[2] + st_[3]);
            sum += __shfl_xor(sum, 16, 64);
            sum += __shfl_xor(sum, 32, 64);
            const float inv = 1.0f / sum;
            #pragma unroll
            for (int tn = 0; tn < 4; ++tn) {
                union { __hip_bfloat16 h4[4]; uint2 u; } pk;
                #pragma unroll
                for (int r = 0; r < 4; ++r) pk.h4[r] = f2b(sco[tn][r] * inv);
                *(uint2*)(S2 + ql * 104 + 16 * tn + 4 * quad) = pk.u;
            }
            #pragma unroll
            for (int ks2 = 0; ks2 < 2; ++ks2) {
                bf16x8 pa = *(const bf16x8*)(S2 + ql * 104 + ks2 * 32 + quad * 8);
                #pragma unroll
                for (int t2 = 0; t2 < 2; ++t2) {
                    bf16x8 vb = *(const bf16x8*)(vT[ii] + (c0 + 16 * t2 + ln) * 72 + ks2 * 32 + quad * 8);
                    oacc[ii][h][t2] = __builtin_amdgcn_mfma_f32_16x16x32_bf16(vb, pa, oacc[ii][h][t2], 0, 0, 0);
                }
            }
        }
    }
    // deferred att-out: packed uint2 (4 consecutive d, own row)
    #pragma unroll
    for (int ii = 0; ii < 2; ++ii)
        #pragma unroll
        for (int h = 0; h < 3; ++h)
            #pragma unroll
            for (int t2 = 0; t2 < 2; ++t2) {
                union { __hip_bfloat16 h4[4]; uint2 u; } pk;
                #pragma unroll
                for (int r = 0; r < 4; ++r) pk.h4[r] = f2b(oacc[ii][h][t2][r]);
                *(uint2*)(xs[ii] + myrow * 104 + h * 32 + 16 * t2 + 4 * quad) = pk.u;
            }

    // ---------- phase C: FFN (FFN1 LDS-pipelined shared wb; FFN2 reg frags) ----------
    bf16x8 cf[2][3];
    #pragma unroll
    for (int ii = 0; ii < 2; ++ii)
        #pragma unroll
        for (int ks = 0; ks < 3; ++ks)
            cf[ii][ks] = *(const bf16x8*)(xs[ii] + myrow * 104 + ks * 32 + quad * 8);

    f32x4 acc2[2][6];
    #pragma unroll
    for (int ii = 0; ii < 2; ++ii)
        #pragma unroll
        for (int ct = 0; ct < 6; ++ct) acc2[ii][ct] = z4;
    bf16x8 w2f[6], w2fn[6];
    for (int jh = 0; jh < 2; ++jh) {
        for (int cc = 0; cc < 4; ++cc) {
            const int j0g = jh * 192 + cc * 48;
            __syncthreads();                                // wb consumers done (and at
                                                            // jh0cc0: all waves past B + cf)
            {
                bf16x8* dst = (bf16x8*)wb;
                dst[tid] = pf0;
                dst[tid + 256] = pf1;
                if (tid + 512 < 624) dst[tid + 512] = pf2;
                if (cc < 3) {
                    const bf16x8* src = (const bf16x8*)(Wc + O_W1T + jh * 19968 + (cc + 1) * 4992);
                    pf0 = src[tid]; pf1 = src[tid + 256];
                    if (tid + 512 < 624) pf2 = src[tid + 512];
                } else {
                    const __hip_bfloat16* nb = Wc + O_W2C + (jh * 6) * 3840;
                    #pragma unroll
                    for (int ct = 0; ct < 6; ++ct)
                        w2f[ct] = *(const bf16x8*)(nb + (ct * 16 + ln) * 40 + quad * 8);
                }
            }
            __syncthreads();
            #pragma unroll
            for (int ii = 0; ii < 2; ++ii) {
                f32x4 a1[3] = {z4, z4, z4};
                #pragma unroll
                for (int ks = 0; ks < 3; ++ks) {
                    #pragma unroll
                    for (int ct = 0; ct < 3; ++ct) {
                        bf16x8 b = *(const bf16x8*)(wb + (ct * 16 + ln) * 104 + ks * 32 + quad * 8);
                        a1[ct] = __builtin_amdgcn_mfma_f32_16x16x32_bf16(b, cf[ii][ks], a1[ct], 0, 0, 0);
                    }
                }
                #pragma unroll
                for (int ct = 0; ct < 3; ++ct) {
                    const int cb = ct * 16 + 4 * quad;
                    union { uint2 u; __hip_bfloat16 h[4]; } bu;
                    bu.u = *(const uint2*)(Wc + O_B1 + j0g + cb);
                    union { __hip_bfloat16 h4[4]; uint2 u; } pk;
                    #pragma unroll
                    for (int r = 0; r < 4; ++r)
                        pk.h4[r] = f2b(fmaxf(a1[ct][r] + b2f(bu.h[r]), 0.f));
                    *(uint2*)(hid[ii] + myrow * 200 + cc * 48 + cb) = pk.u;
                }
            }
        }
        for (int kc = 0; kc < 6; ++kc) {
            if (kc < 5) {
                const __hip_bfloat16* nb = Wc + O_W2C + (jh * 6 + kc + 1) * 3840;
                #pragma unroll
                for (int ct = 0; ct < 6; ++ct)
                    w2fn[ct] = *(const bf16x8*)(nb + (ct * 16 + ln) * 40 + quad * 8);
            } else if (jh == 0) {
                const bf16x8* src = (const bf16x8*)(Wc + O_W1T + 19968);
                pf0 = src[tid]; pf1 = src[tid + 256];
                if (tid + 512 < 624) pf2 = src[tid + 512];
            }
            #pragma unroll
            for (int ii = 0; ii < 2; ++ii) {
                bf16x8 a = *(const bf16x8*)(hid[ii] + myrow * 200 + kc * 32 + quad * 8);
                #pragma unroll
                for (int ct = 0; ct < 6; ++ct)
                    acc2[ii][ct] = __builtin_amdgcn_mfma_f32_16x16x32_bf16(a, w2f[ct], acc2[ii][ct], 0, 0, 0);
            }
            if (kc < 5) {
                #pragma unroll
                for (int ct = 0; ct < 6; ++ct) w2f[ct] = w2fn[ct];
            }
        }
    }

    #pragma unroll
    for (int ii = 0; ii < 2; ++ii) {
        __hip_bfloat16* Mg = M + (size_t)(n0b + ii * 2048) * 6144;
        #pragma unroll
        for (int ct = 0; ct < 6; ++ct) {
            int d = ct * 16 + ln;
            float bb = b2f(Wc[O_B2 + d]);
            union { __hip_bfloat16 h4[4]; uint2 u; } pk;
            #pragma unroll
            for (int r = 0; r < 4; ++r) pk.h4[r] = f2b(acc2[ii][ct][r] + bb);
            *(uint2*)((char*)Mg + (size_t)(d * 64 + rowb) * 2) = pk.u;
        }
    }
}

// Y = A @ We + be, mean/var fused. R16-exact: BK=128 (48 iters),
// global_load_lds width-16 staging; linear LDS dest + pre-swizzled global
// source + swizzled reads (key=row&7, XOR byte bits 4-6). 64 KiB LDS.
__global__ __launch_bounds__(256) void gemm_kernel(
    const __hip_bfloat16* __restrict__ A,    // 4096 x 6144 (M workspace)
    const __hip_bfloat16* __restrict__ Wc,
    const float* __restrict__ be,            // fp32 bias (512)
    float* __restrict__ Y,                   // 4096 x 512
    float* __restrict__ sums)                // 2 floats (pre-zeroed)
{
    __shared__ __align__(16) char gsm[65536];               // As[2]@0, Bs[2]@32768
    const int row0 = blockIdx.x * 64, nt = blockIdx.y, col0 = nt * 64;
    const int tid = threadIdx.x;
    const int w = tid >> 6, lane = tid & 63, quad = lane >> 4, ln = lane & 15;
    const __hip_bfloat16* Bsrc = Wc + O_WET + (size_t)nt * 96 * 4096;

    const f32x4 z4 = {0.f, 0.f, 0.f, 0.f};
    f32x4 acc[4] = {z4, z4, z4, z4};

    auto stage = [&](int buf, int kt) {
        char* Ab = gsm + buf * 16384;
        char* Bb = gsm + 32768 + buf * 16384;
        #pragma unroll
        for (int j = 0; j < 4; ++j) {
            const int b = j * 4096 + tid * 16;
            const int row = b >> 8;
            const int s = b ^ ((row & 7) << 4);
            const int col = (s & 255) >> 1;
            gload16(A + (size_t)(row0 + row) * 6144 + kt * 128 + col,
                    Ab + j * 4096 + w * 1024);
            gload16(Bsrc + (size_t)(2 * kt + (col >> 6)) * 4096 + row * 64 + (col & 63),
                    Bb + j * 4096 + w * 1024);
        }
    };

    stage(0, 0);
    __syncthreads();

    for (int kt = 0; kt < 48; ++kt) {
        const int cur = kt & 1;
        if (kt < 47) stage(cur ^ 1, kt + 1);
        const char* Ab = gsm + cur * 16384;
        const char* Bb = gsm + 32768 + cur * 16384;
        #pragma unroll
        for (int ks = 0; ks < 4; ++ks) {
            const int ra = ((16 * w + ln) << 8) + ks * 64 + quad * 16;
            bf16x8 a = *(const bf16x8*)(Ab + (ra ^ ((ln & 7) << 4)));
            #pragma unroll
            for (int tn = 0; tn < 4; ++tn) {
                const int rb = ((16 * tn + ln) << 8) + ks * 64 + quad * 16;
                bf16x8 b = *(const bf16x8*)(Bb + (rb ^ ((ln & 7) << 4)));
                acc[tn] = __builtin_amdgcn_mfma_f32_16x16x32_bf16(a, b, acc[tn], 0, 0, 0);
            }
        }
        __syncthreads();
    }

    float s = 0.f, s2 = 0.f;
    #pragma unroll
    for (int tn = 0; tn < 4; ++tn) {
        int col = col0 + 16 * tn + ln;
        float bb = be[col];
        #pragma unroll
        for (int r = 0; r < 4; ++r) {
            float v = acc[tn][r] + bb;
            Y[(size_t)(row0 + 16 * w + quad * 4 + r) * 512 + col] = v;
            s += v; s2 += v * v;
        }
    }
    #pragma unroll
    for (int off = 1; off < 64; off <<= 1) {
        s  += __shfl_xor(s, off, 64);
        s2 += __shfl_xor(s2, off, 64);
    }
    float* r1s = (float*)gsm;
    float* r2s = r1s + 4;
    if (lane == 0) { r1s[w] = s; r2s[w] = s2; }
    __syncthreads();
    if (tid == 0) {
        atomicAdd(&sums[0], r1s[0] + r1s[1] + r1s[2] + r1s[3]);
        atomicAdd(&sums[1], r2s[0] + r2s[1] + r2s[2] + r2s[3]);
    }
}

__global__ __launch_bounds__(256) void final_kernel(
    const float* __restrict__ Y, const int* __restrict__ bids,
    const float* __restrict__ sums, const float* __restrict__ r_enc,
    float* __restrict__ out)
{
    const int bt = blockIdx.x;
    const int b = bt >> 10, t = bt & 1023;
    const float mu = sums[0] * (1.0f / 2097152.0f);
    const float var = sums[1] * (1.0f / 2097152.0f) - mu * mu;
    const float rstd = rsqrtf(var + 1e-8f);
    const int* bid = bids + b * 1024;
    const int my = bid[t];
    const bool is_start = (t == 0) || (bid[t - 1] != my);
    int t2 = t + 1;
    float invc = 0.f;
    if (is_start) {
        while (t2 < 1024 && bid[t2] == my) ++t2;
        invc = 1.0f / (float)(t2 - t);
    }
    for (int e = threadIdx.x; e < 512; e += 256) {
        const size_t base = (size_t)bt * 512 + e;
        float res = (Y[base] - mu) * rstd + r_enc[base];
        if (is_start) {
            float s = 0.f;
            for (int tt = t; tt < t2; ++tt)
                s += (Y[((size_t)(b * 1024 + tt)) * 512 + e] - mu) * rstd;
            res += s * invc;
        }
        out[base] = res;
    }
}

extern "C" void kernel_launch(void* const* d_in, const int* in_sizes, int n_in,
                              void* d_out, int out_size, void* d_ws, size_t ws_size,
                              hipStream_t stream) {
    PtrTab tab;
    for (int i = 0; i < 16; ++i) tab.p[i] = d_in[i];

    char* ws = (char*)d_ws;
    __hip_bfloat16* M  = (__hip_bfloat16*)ws;
    float* Y           = (float*)(ws + 50331648);
    float* sums        = (float*)(ws + 58720256);
    int*   bids        = (int*)(ws + 58720320);
    __hip_bfloat16* Wc = (__hip_bfloat16*)(ws + 58736768);

    prep_kernel<<<768, 256, 0, stream>>>(tab, Wc, sums, bids);
    attn_ffn_kernel<<<2048, 256, 0, stream>>>((const float*)d_in[0], Wc, M);
    gemm_kernel<<<dim3(64, 8), 256, 0, stream>>>(M, Wc, (const float*)d_in[15], Y, sums);
    final_kernel<<<4096, 256, 0, stream>>>(Y, bids, sums, (const float*)d_in[2], (float*)d_out);
}